// Round 5
// baseline (161.374 us; speedup 1.0000x reference)
//
#include <hip/hip_runtime.h>
#include <cmath>

// Cox partial likelihood (Breslow) loss, N=16384.
// denom[i] = sum_j [t_j >= t_i] * exp(est_j)
// loss = sum_i ev_i * (log(denom[i]) - est[i]) / max(sum ev, 1)
//
// R5: single fused kernel (split-K fixup via device atomics), sorted-pair
// inner loop (5 VALU ops per 2 j's instead of 6).

#define RPT    8                  // i's per lane
#define WAVES  8                  // waves per block
#define NTHR   (64 * WAVES)       // 512 threads
#define ITILE  (64 * RPT)         // 512 i's per block
#define JSPLIT 32                 // j-splits (blockIdx.y)
#define JCHUNK 512                // j's per block
#define NITILE 32                 // N / ITILE

__global__ __launch_bounds__(NTHR)
void cox_fused(const float* __restrict__ est,
               const float* __restrict__ target,
               float* __restrict__ pden,    // [JSPLIT][n]
               float2* __restrict__ ptile,  // [NITILE] (loss, ev) partials
               int* __restrict__ cnt,       // [NITILE+1], zeroed via memset node
               float* __restrict__ out,
               int n) {
    __shared__ float2 ste[JCHUNK];           // raw (t, e)           4 KB
    __shared__ float4 spq[JCHUNK / 2];       // sorted pairs         4 KB
    __shared__ float  sden[WAVES][ITILE];    // per-wave partials   16 KB
    __shared__ float2 sred[WAVES];
    __shared__ int    sflag;

    const int tid   = threadIdx.x;
    const int il    = tid & 63;
    const int wave  = __builtin_amdgcn_readfirstlane(tid >> 6);
    const int bx    = blockIdx.x;            // i-tile
    const int by    = blockIdx.y;            // j-split
    const int ibase = bx * ITILE;

    // ---- stage this block's j-chunk (exp fused) ----
    {
        const int jg = by * JCHUNK + tid;
        ste[tid] = make_float2(target[2 * jg], expf(est[jg]));
    }

    // ---- per-lane i state ----
    float ti[RPT], acc[RPT];
    #pragma unroll
    for (int r = 0; r < RPT; ++r) {
        ti[r]  = target[2 * (ibase + il + 64 * r)];
        acc[r] = 0.f;
    }
    __syncthreads();

    // ---- build sorted pairs: (t_lo, t_hi, e_hi, e_lo+e_hi) ----
    if (tid < JCHUNK / 2) {
        float2 a = ste[2 * tid], b = ste[2 * tid + 1];
        float ta  = fminf(a.x, b.x);
        float tb  = fmaxf(a.x, b.x);
        float ehi = (a.x <= b.x) ? b.y : a.y;
        spq[tid] = make_float4(ta, tb, ehi, a.y + b.y);
    }
    __syncthreads();

    // ---- scan this wave's 32 pairs (64 j's): broadcast ds_read_b128 ----
    // ti <= t_lo -> both included (+e_lo+e_hi); t_lo < ti <= t_hi -> +e_hi.
    const int fbase = wave * (JCHUNK / 2 / WAVES);   // 32 float4 per wave
    #pragma unroll 4
    for (int it = 0; it < JCHUNK / 2 / WAVES; it += 2) {
        float4 p0 = spq[fbase + it];
        float4 p1 = spq[fbase + it + 1];
        #pragma unroll
        for (int r = 0; r < RPT; ++r) {
            acc[r] += (ti[r] <= p0.x) ? p0.w : ((ti[r] <= p0.y) ? p0.z : 0.f);
            acc[r] += (ti[r] <= p1.x) ? p1.w : ((ti[r] <= p1.y) ? p1.z : 0.f);
        }
    }

    // ---- reduce 8 waves' partials per i, write this j-split's partial ----
    #pragma unroll
    for (int r = 0; r < RPT; ++r) sden[wave][(r << 6) + il] = acc[r];
    __syncthreads();

    float d = 0.f;
    #pragma unroll
    for (int w = 0; w < WAVES; ++w) d += sden[w][tid];
    pden[by * n + ibase + tid] = d;

    // ---- arrival: last block for this i-tile does the fixup ----
    __threadfence();              // make pden stores device-visible
    __syncthreads();              // all threads' fences complete
    if (tid == 0) sflag = (atomicAdd(&cnt[bx], 1) == JSPLIT - 1);
    __syncthreads();
    if (!sflag) return;
    __threadfence();              // acquire side

    // fixup: full denom + per-i contribution + block reduce
    const int i = ibase + tid;
    float dd = 0.f;
    #pragma unroll
    for (int s = 0; s < JSPLIT; ++s) dd += pden[s * n + i];
    float ev      = (target[2 * i + 1] != 0.f) ? 1.f : 0.f;
    float contrib = ev * (logf(dd) - est[i]);

    #pragma unroll
    for (int off = 32; off > 0; off >>= 1) {
        contrib += __shfl_down(contrib, off, 64);
        ev      += __shfl_down(ev, off, 64);
    }
    if (il == 0) sred[wave] = make_float2(contrib, ev);
    __syncthreads();

    if (tid == 0) {
        float l = 0.f, v = 0.f;
        #pragma unroll
        for (int w = 0; w < WAVES; ++w) { l += sred[w].x; v += sred[w].y; }
        ptile[bx] = make_float2(l, v);
        __threadfence();
        sflag = (atomicAdd(&cnt[NITILE], 1) == NITILE - 1);
    }
    __syncthreads();
    if (!sflag) return;
    __threadfence();

    // ---- final reduction over the 32 i-tile partials (one wave) ----
    if (tid < 64) {
        float l = (tid < NITILE) ? ptile[tid].x : 0.f;
        float v = (tid < NITILE) ? ptile[tid].y : 0.f;
        #pragma unroll
        for (int off = 32; off > 0; off >>= 1) {
            l += __shfl_down(l, off, 64);
            v += __shfl_down(v, off, 64);
        }
        if (tid == 0) out[0] = l / fmaxf(v, 1.f);
    }
}

// ---------------------------------------------------------------------------
extern "C" void kernel_launch(void* const* d_in, const int* in_sizes, int n_in,
                              void* d_out, int out_size, void* d_ws, size_t ws_size,
                              hipStream_t stream) {
    const float* est    = (const float*)d_in[0];
    const float* target = (const float*)d_in[1];
    float*       out    = (float*)d_out;

    const int n = in_sizes[0];                 // 16384

    float*  ws    = (float*)d_ws;
    float*  pden  = ws;                              // [JSPLIT][n] = 2 MB
    float2* ptile = (float2*)(ws + JSPLIT * n);      // [NITILE]
    int*    cnt   = (int*)(ptile + NITILE);          // [NITILE+1]

    // counters must start at 0 every call (ws is poisoned 0xAA, not re-zeroed)
    hipMemsetAsync(cnt, 0, (NITILE + 1) * sizeof(int), stream);

    dim3 grid(n / ITILE, JSPLIT);                    // (32, 32)
    cox_fused<<<grid, NTHR, 0, stream>>>(est, target, pden, ptile, cnt, out, n);
}

// Round 6
// 27.847 us; speedup vs baseline: 5.7951x; 5.7951x over previous
//
#include <hip/hip_runtime.h>
#include <cmath>

// Cox partial likelihood (Breslow) loss, N=16384.
// denom[i] = sum_j [t_j >= t_i] * exp(est_j)
// loss = sum_i ev_i * (log(denom[i]) - est[i]) / max(sum ev, 1)
//
// R6 = R4 (3-kernel, register-blocked i, LDS broadcast j) + sorted-pair
// inner loop (2.5 VALU ops per j instead of 3). NO device fences (R5 lesson:
// cross-XCD coherence ops cost >>100us at 1024 blocks; a launch is 2us).

#define RPT    8                  // i's per lane (register-blocked)
#define WAVES  8                  // waves per block
#define NTHR   (64 * WAVES)       // 512 threads
#define ITILE  (64 * RPT)         // 512 i's per block
#define JSPLIT 32                 // j-range split across blockIdx.y
#define JCHUNK 512                // j's per block (N / JSPLIT)
#define QWAVE  (JCHUNK / 2 / WAVES)  // 32 sorted pairs per wave

// ---------------------------------------------------------------------------
// Kernel 1: partial denom. exp() fused into LDS staging.
// Grid: (N/ITILE, JSPLIT) = (32, 32). Block: 512 threads = 8 waves.
__global__ __launch_bounds__(NTHR)
void cox_denom(const float* __restrict__ est,
               const float* __restrict__ target,
               float* __restrict__ pden,   // [JSPLIT][n]
               int n) {
    __shared__ float2 ste[JCHUNK];          // raw (t, e)            4 KB
    __shared__ float4 spq[JCHUNK / 2];      // sorted pairs          4 KB
    __shared__ float  sden[WAVES][ITILE];   // per-wave partials    16 KB

    const int tid   = threadIdx.x;
    const int il    = tid & 63;
    const int wave  = __builtin_amdgcn_readfirstlane(tid >> 6);
    const int ibase = blockIdx.x * ITILE;

    // ---- stage this block's j-chunk into LDS (exp fused) ----
    {
        const int jg = blockIdx.y * JCHUNK + tid;
        ste[tid] = make_float2(target[2 * jg], expf(est[jg]));
    }

    // ---- per-lane i state ----
    float ti[RPT], acc[RPT];
    #pragma unroll
    for (int r = 0; r < RPT; ++r) {
        ti[r]  = target[2 * (ibase + il + 64 * r)];
        acc[r] = 0.f;
    }
    __syncthreads();

    // ---- build sorted pairs: (t_lo, t_hi, e_hi, e_lo+e_hi) ----
    if (tid < JCHUNK / 2) {
        float2 a = ste[2 * tid], b = ste[2 * tid + 1];
        float tlo = fminf(a.x, b.x);
        float thi = fmaxf(a.x, b.x);
        float ehi = (a.x <= b.x) ? b.y : a.y;
        spq[tid] = make_float4(tlo, thi, ehi, a.y + b.y);
    }
    __syncthreads();

    // ---- scan this wave's 32 pairs (64 j's): uniform ds_read_b128 ----
    // ti <= t_lo -> both j's included (+e_lo+e_hi); else t_lo < ti <= t_hi
    // -> only the later-time j (+e_hi); else neither.
    const int fbase = wave * QWAVE;
    #pragma unroll 4
    for (int it = 0; it < QWAVE; it += 2) {
        float4 p0 = spq[fbase + it];
        float4 p1 = spq[fbase + it + 1];
        #pragma unroll
        for (int r = 0; r < RPT; ++r) {
            acc[r] += (ti[r] <= p0.x) ? p0.w : ((ti[r] <= p0.y) ? p0.z : 0.f);
            acc[r] += (ti[r] <= p1.x) ? p1.w : ((ti[r] <= p1.y) ? p1.z : 0.f);
        }
    }

    // ---- reduce 8 waves' partials per i ----
    #pragma unroll
    for (int r = 0; r < RPT; ++r) sden[wave][(r << 6) + il] = acc[r];
    __syncthreads();

    float d = 0.f;
    #pragma unroll
    for (int w = 0; w < WAVES; ++w) d += sden[w][tid];
    pden[blockIdx.y * n + ibase + tid] = d;
}

// ---------------------------------------------------------------------------
// Kernel 2: combine j-split partials, per-i contribution, per-block reduce.
__global__ __launch_bounds__(256)
void cox_combine(const float* __restrict__ est,
                 const float* __restrict__ target,
                 const float* __restrict__ pden,
                 float* __restrict__ ploss,
                 float* __restrict__ pev,
                 int n) {
    __shared__ float sl[4], sv[4];
    const int tid = threadIdx.x;
    const int i   = blockIdx.x * 256 + tid;

    float d = 0.f;
    #pragma unroll
    for (int s = 0; s < JSPLIT; ++s) d += pden[s * n + i];
    float ev      = (target[2 * i + 1] != 0.f) ? 1.f : 0.f;
    float contrib = ev * (logf(d) - est[i]);

    #pragma unroll
    for (int off = 32; off > 0; off >>= 1) {
        contrib += __shfl_down(contrib, off, 64);
        ev      += __shfl_down(ev, off, 64);
    }
    if ((tid & 63) == 0) { sl[tid >> 6] = contrib; sv[tid >> 6] = ev; }
    __syncthreads();
    if (tid == 0) {
        ploss[blockIdx.x] = sl[0] + sl[1] + sl[2] + sl[3];
        pev[blockIdx.x]   = sv[0] + sv[1] + sv[2] + sv[3];
    }
}

// ---------------------------------------------------------------------------
// Kernel 3: final reduction of block partials -> scalar loss.
__global__ void cox_finalize(const float* __restrict__ ploss,
                             const float* __restrict__ pev,
                             float* __restrict__ out,
                             int nblocks) {
    const int tid = threadIdx.x;  // 64 threads = one wave
    float l = 0.f, v = 0.f;
    for (int k = tid; k < nblocks; k += 64) {
        l += ploss[k];
        v += pev[k];
    }
    #pragma unroll
    for (int off = 32; off > 0; off >>= 1) {
        l += __shfl_down(l, off, 64);
        v += __shfl_down(v, off, 64);
    }
    if (tid == 0) out[0] = l / fmaxf(v, 1.f);
}

// ---------------------------------------------------------------------------
extern "C" void kernel_launch(void* const* d_in, const int* in_sizes, int n_in,
                              void* d_out, int out_size, void* d_ws, size_t ws_size,
                              hipStream_t stream) {
    const float* est    = (const float*)d_in[0];
    const float* target = (const float*)d_in[1];
    float*       out    = (float*)d_out;

    const int n        = in_sizes[0];          // 16384
    const int niblocks = n / ITILE;            // 32
    const int ncblocks = n / 256;              // 64

    float* ws    = (float*)d_ws;
    float* pden  = ws;                         // [JSPLIT][n] = 2 MB
    float* ploss = pden + JSPLIT * n;          // [ncblocks]
    float* pev   = ploss + ncblocks;           // [ncblocks]

    dim3 grid(niblocks, JSPLIT);
    cox_denom<<<grid, NTHR, 0, stream>>>(est, target, pden, n);
    cox_combine<<<ncblocks, 256, 0, stream>>>(est, target, pden, ploss, pev, n);
    cox_finalize<<<1, 64, 0, stream>>>(ploss, pev, out, ncblocks);
}

// Round 7
// 27.290 us; speedup vs baseline: 5.9133x; 1.0204x over previous
//
#include <hip/hip_runtime.h>
#include <cmath>

// Cox partial likelihood (Breslow) loss, N=16384.
// denom[i] = sum_j [t_j >= t_i] * exp(est_j)
// loss = sum_i ev_i * (log(denom[i]) - est[i]) / max(sum ev, 1)
//
// R7: O(N log N). K1 rank-sorts 512-element chunks (unique u64 keys, no
// atomics -> deterministic) + suffix-sums exp(est) in sorted order.
// K2: per i, branchless lower_bound in each of 32 sorted chunks; denom =
// sum of chunk suffix values. K3: finalize. No device fences (R5 lesson).

#define NCHUNK 32
#define CSZ    512                   // chunk size (= block size of K1)
#define SUBS   8                     // sub-threads per i in K2
#define CPS    (NCHUNK / SUBS)       // 4 chunks per sub-thread
#define K2THR  512                   // K2 block size -> 64 i's per block

// ---------------------------------------------------------------------------
// K1: per-chunk rank sort + suffix sums of e = exp(est).
// Keys (bits(t)<<32)|tid are unique -> rank is a permutation (t>=0 so the
// float bit pattern is order-preserving; t ~ uniform[0,1) here).
__global__ __launch_bounds__(CSZ)
void cox_sort(const float2* __restrict__ tg,
              const float* __restrict__ est,
              float* __restrict__ ts,    // [NCHUNK*CSZ] sorted t
              float* __restrict__ ss) {  // [NCHUNK*CSZ] suffix sums of e
    __shared__ unsigned long long skey[CSZ];  // 4 KB
    __shared__ float sst[CSZ];                // 2 KB
    __shared__ float sse[CSZ];                // 2 KB

    const int tid = threadIdx.x;
    const int j   = blockIdx.x * CSZ + tid;

    const float tj = tg[j].x;
    const float ej = expf(est[j]);
    const unsigned long long key =
        ((unsigned long long)__float_as_uint(tj) << 32) | (unsigned)tid;
    skey[tid] = key;
    __syncthreads();

    // rank = #{k : key_k < key}  (broadcast LDS reads, 2 VALU per element)
    int rank = 0;
    const ulonglong2* k2 = (const ulonglong2*)skey;
    #pragma unroll 8
    for (int k = 0; k < CSZ / 2; ++k) {
        ulonglong2 p = k2[k];
        rank += (p.x < key) ? 1 : 0;
        rank += (p.y < key) ? 1 : 0;
    }

    sst[rank] = tj;       // scatter into sorted position
    sse[rank] = ej;
    __syncthreads();

    // inclusive suffix scan of sse (Hillis-Steele, fixed order -> determ.)
    #pragma unroll
    for (int off = 1; off < CSZ; off <<= 1) {
        float add = (tid + off < CSZ) ? sse[tid + off] : 0.f;
        __syncthreads();
        sse[tid] += add;
        __syncthreads();
    }

    ts[blockIdx.x * CSZ + tid] = sst[tid];
    ss[blockIdx.x * CSZ + tid] = sse[tid];
}

// ---------------------------------------------------------------------------
// K2: per-i denom via 32 branchless lower_bounds (L2-resident table),
// then contribution + block reduction. 8 subs per i, 4 chunks each.
__global__ __launch_bounds__(K2THR)
void cox_search(const float2* __restrict__ tg,
                const float* __restrict__ est,
                const float* __restrict__ ts,
                const float* __restrict__ ss,
                float* __restrict__ ploss,
                float* __restrict__ pev) {
    __shared__ float sl[K2THR / 64], sv[K2THR / 64];

    const int tid = threadIdx.x;
    const int sub = tid & (SUBS - 1);
    const int i   = blockIdx.x * (K2THR / SUBS) + (tid >> 3);

    const float ti = tg[i].x;

    float d = 0.f;
    #pragma unroll
    for (int cc = 0; cc < CPS; ++cc) {
        const int c = sub * CPS + cc;
        const float* tsc = ts + (c << 9);
        // branchless lower_bound: pos = #{k : tsc[k] < ti}
        int pos = 0;
        #pragma unroll
        for (int s = 256; s >= 1; s >>= 1)
            pos += (tsc[pos + s - 1] < ti) ? s : 0;   // max probe idx 510
        pos += (tsc[pos] < ti) ? 1 : 0;               // pos in [0,512]
        d += (pos < CSZ) ? ss[(c << 9) + pos] : 0.f;  // suffix = sum t>=ti
    }

    // combine the 8 subs' partial denoms (fixed tree -> deterministic)
    d += __shfl_down(d, 4, 8);
    d += __shfl_down(d, 2, 8);
    d += __shfl_down(d, 1, 8);

    float contrib = 0.f, ev = 0.f;
    if (sub == 0) {
        ev      = (tg[i].y != 0.f) ? 1.f : 0.f;
        contrib = ev * (logf(d) - est[i]);
    }
    #pragma unroll
    for (int off = 32; off > 0; off >>= 1) {
        contrib += __shfl_down(contrib, off, 64);
        ev      += __shfl_down(ev, off, 64);
    }
    if ((tid & 63) == 0) { sl[tid >> 6] = contrib; sv[tid >> 6] = ev; }
    __syncthreads();
    if (tid == 0) {
        float l = 0.f, v = 0.f;
        #pragma unroll
        for (int w = 0; w < K2THR / 64; ++w) { l += sl[w]; v += sv[w]; }
        ploss[blockIdx.x] = l;
        pev[blockIdx.x]   = v;
    }
}

// ---------------------------------------------------------------------------
// K3: final reduction of block partials -> scalar loss.
__global__ void cox_finalize(const float* __restrict__ ploss,
                             const float* __restrict__ pev,
                             float* __restrict__ out,
                             int nblocks) {
    const int tid = threadIdx.x;  // one wave
    float l = 0.f, v = 0.f;
    for (int k = tid; k < nblocks; k += 64) {
        l += ploss[k];
        v += pev[k];
    }
    #pragma unroll
    for (int off = 32; off > 0; off >>= 1) {
        l += __shfl_down(l, off, 64);
        v += __shfl_down(v, off, 64);
    }
    if (tid == 0) out[0] = l / fmaxf(v, 1.f);
}

// ---------------------------------------------------------------------------
extern "C" void kernel_launch(void* const* d_in, const int* in_sizes, int n_in,
                              void* d_out, int out_size, void* d_ws, size_t ws_size,
                              hipStream_t stream) {
    const float*  est = (const float*)d_in[0];
    const float2* tg  = (const float2*)d_in[1];   // target[N][2] = (t, event)
    float*        out = (float*)d_out;

    const int n        = in_sizes[0];             // 16384
    const int nchunks  = n / CSZ;                 // 32
    const int nblocks2 = n / (K2THR / SUBS);      // 256

    float* ws    = (float*)d_ws;
    float* ts    = ws;                            // [n]
    float* ss    = ws + n;                        // [n]
    float* ploss = ws + 2 * n;                    // [nblocks2]
    float* pev   = ploss + nblocks2;              // [nblocks2]

    cox_sort<<<nchunks, CSZ, 0, stream>>>(tg, est, ts, ss);
    cox_search<<<nblocks2, K2THR, 0, stream>>>(tg, est, ts, ss, ploss, pev);
    cox_finalize<<<1, 64, 0, stream>>>(ploss, pev, out, nblocks2);
}